// Round 7
// baseline (303.780 us; speedup 1.0000x reference)
//
#include <hip/hip_runtime.h>

typedef __bf16 bf16;
typedef __bf16 bf16x8 __attribute__((ext_vector_type(8)));
typedef __bf16 bf16x4 __attribute__((ext_vector_type(4)));
typedef float  f32x4  __attribute__((ext_vector_type(4)));

#define T_TOTAL 9792
#define EMBED   1024
#define NHEAD   16
#define HDIM    64

// Fixed problem geometry (LENGTHS are compile-time constants of this problem).
__constant__ int c_seq_start13[13] = {0,1024,1792,2688,3200,4224,4864,5888,6656,7168,8064,9088,9792};
// 128-row q-tiles per seq: [8,6,7,4,8,5,8,6,4,7,8,6] -> cumsum
__constant__ int c_qtiles_cum[13] = {0,8,14,21,25,33,38,46,52,56,63,71,77};

typedef __attribute__((address_space(1))) unsigned int gu32;
typedef __attribute__((address_space(3))) unsigned int lu32;

__device__ __forceinline__ void load_lds16(const void* g, void* l) {
    __builtin_amdgcn_global_load_lds((gu32*)g, (lu32*)l, 16, 0, 0);
}

__device__ __forceinline__ f32x4 mfma16(bf16x8 a, bf16x8 b, f32x4 c) {
    return __builtin_amdgcn_mfma_f32_16x16x32_bf16(a, b, c, 0, 0, 0);
}

// XCD-chunked remap (T1). MI355X: 8 XCDs, consecutive blockIdx round-robins
// XCDs; nwg%8==0 for all our grids -> bijective contiguous chunks per XCD.
__device__ __forceinline__ int xcd_chunk(int bid, int chunk) {
    return (bid & 7) * chunk + (bid >> 3);
}

// ---------------------------------------------------------------------------
// Fused dtype canonicalization: all 10 tensors in one dispatch.
// Discriminator: cos[0][0]==1.0 exactly -> fp32 first u16 is 0x0000.
// ---------------------------------------------------------------------------
struct CvtArgs {
    const void* src[10];
    bf16*       dst[10];
    int         n[10];
    int         cum[10];   // block offset of each segment
};

__global__ void to_bf16_fused(CvtArgs a, const unsigned short* __restrict__ disc)
{
    const bool f32 = (disc[0] == 0);
    const int blk = blockIdx.x;
    int seg = 0;
    #pragma unroll
    for (int i = 1; i < 10; ++i) if (blk >= a.cum[i]) seg = i;
    int i0 = (blk - a.cum[seg]) * 2048 + threadIdx.x * 8;
    if (i0 >= a.n[seg]) return;
    bf16x8 o;
    if (f32) {
        const float4* s = (const float4*)((const float*)a.src[seg] + i0);
        float4 x = s[0], y = s[1];
        o[0]=(bf16)x.x; o[1]=(bf16)x.y; o[2]=(bf16)x.z; o[3]=(bf16)x.w;
        o[4]=(bf16)y.x; o[5]=(bf16)y.y; o[6]=(bf16)y.z; o[7]=(bf16)y.w;
    } else {
        o = *(const bf16x8*)((const bf16*)a.src[seg] + i0);
    }
    *(bf16x8*)(a.dst[seg] + i0) = o;
}

// ---------------------------------------------------------------------------
// Shared GEMM core: acc = A[m0:+128] @ W[n0:+128]^T  (K=1024, BK=64).
// R4-verified structure (77 us, 0 bank conflicts, ~800 TF): single
// 2x128x64 LDS, XOR-swizzled on the GLOBAL side of staging, 2 blocks/CU.
// Scheduling experiments R1/R2/R3/R5 all regressed vs this — frozen.
// ---------------------------------------------------------------------------
__device__ __forceinline__
void gemm_core(const bf16* __restrict__ A, const bf16* __restrict__ W,
               int M, int m0, int n0, f32x4 (&acc)[4][4],
               bf16* lA, bf16* lB)
{
    const int tid  = threadIdx.x;
    const int wave = tid >> 6, lane = tid & 63;
    const int lrow = lane >> 3;
    const int gsw  = (lane & 7) ^ lrow;
    const int ln   = lane & 15, lq = lane >> 4;
    const int e7   = ln & 7;
    const int wm = (wave & 1) * 64,  wn = (wave >> 1) * 64;

    for (int k0 = 0; k0 < 1024; k0 += 64) {
        __syncthreads();
        for (int j = 0; j < 4; ++j) {
            int r = j * 32 + wave * 8;
            int gr = m0 + r + lrow; if (gr > M - 1) gr = M - 1;
            load_lds16(A + (size_t)gr * EMBED + k0 + gsw * 8, &lA[r * 64]);
            load_lds16(W + (size_t)(n0 + r + lrow) * EMBED + k0 + gsw * 8, &lB[r * 64]);
        }
        __syncthreads();
        #pragma unroll
        for (int kb = 0; kb < 2; ++kb) {
            bf16x8 af[4], bfr[4];
            #pragma unroll
            for (int i = 0; i < 4; ++i)
                af[i]  = *(const bf16x8*)&lA[(wm + i * 16 + ln) * 64 + (((kb * 4 + lq) ^ e7) * 8)];
            #pragma unroll
            for (int i = 0; i < 4; ++i)
                bfr[i] = *(const bf16x8*)&lB[(wn + i * 16 + ln) * 64 + (((kb * 4 + lq) ^ e7) * 8)];
            #pragma unroll
            for (int mi = 0; mi < 4; ++mi)
                #pragma unroll
                for (int ni = 0; ni < 4; ++ni)
                    acc[mi][ni] = mfma16(af[mi], bfr[ni], acc[mi][ni]);
        }
    }
}

// Supertile block map: 8 x-tiles per super-column x all NY, L2/L3 locality.
__device__ __forceinline__ void map_block(int L, int NY, int& x, int& y)
{
    const int per = 8 * NY;
    const int full = 9 * per;          // 72 of 77 x-tiles in full supercols
    if (L < full) { int sc = L / per, rem = L % per; x = sc * 8 + (rem & 7); y = rem >> 3; }
    else          { int rem = L - full; x = 72 + rem % 5; y = rem / 5; }
}

// ---------------------------------------------------------------------------
// Q+K GEMM. 1D grid 77*16 (=8*154, XCD-chunked). which = y>>3 in {0,1}.
// Epilogue: bias (Q only) + RoPE on fp32 acc.
// ---------------------------------------------------------------------------
__global__ __launch_bounds__(256, 2)
void gemm_qk(const bf16* __restrict__ A,
             const bf16* __restrict__ Wq, const bf16* __restrict__ Wk,
             const bf16* __restrict__ qb,
             const bf16* __restrict__ cosb, const bf16* __restrict__ sinb,
             bf16* __restrict__ Cq, bf16* __restrict__ Ck, int M)
{
    __shared__ __align__(16) bf16 lA[128 * 64];
    __shared__ __align__(16) bf16 lB[128 * 64];

    int x, yy;
    map_block(xcd_chunk(blockIdx.x, 154), 16, x, yy);
    const int which = yy >> 3;
    const int m0 = x * 128, n0 = (yy & 7) * 128;

    const bf16* W = which ? Wk : Wq;
    f32x4 acc[4][4] = {};
    gemm_core(A, W, M, m0, n0, acc, lA, lB);

    const int tid  = threadIdx.x;
    const int wave = tid >> 6, lane = tid & 63;
    const int ln   = lane & 15, lq = lane >> 4;
    const int wm = (wave & 1) * 64,  wn = (wave >> 1) * 64;

    bf16* C = which ? Ck : Cq;
    const bf16* bias = which ? nullptr : qb;
    #pragma unroll
    for (int mi = 0; mi < 4; ++mi) {
        int trow = m0 + wm + mi * 16 + lq * 4;
        if (trow >= M) continue;
        #pragma unroll
        for (int ni = 0; ni < 2; ++ni) {
            int d    = ni * 16 + ln;           // in [0,32)
            int col0 = n0 + wn + d;
            int col1 = col0 + 32;
            float b0 = bias ? (float)bias[col0] : 0.0f;
            float b1 = bias ? (float)bias[col1] : 0.0f;
            #pragma unroll
            for (int r = 0; r < 4; ++r) {
                int t = trow + r;
                float c = (float)cosb[t * HDIM + d];
                float s = (float)sinb[t * HDIM + d];
                float x0 = acc[mi][ni][r] + b0;
                float x1 = acc[mi][ni + 2][r] + b1;
                C[(size_t)t * EMBED + col0] = (bf16)(x0 * c - x1 * s);
                C[(size_t)t * EMBED + col1] = (bf16)(x1 * c + x0 * s);
            }
        }
    }
}

// ---------------------------------------------------------------------------
// V GEMM. 1D grid 77*8 (=8*77, XCD-chunked).
// Epilogue: bias + direct transposed store Vt[(h*64+d) * T + t].
// ---------------------------------------------------------------------------
__global__ __launch_bounds__(256, 2)
void gemm_v(const bf16* __restrict__ A, const bf16* __restrict__ Wv,
            const bf16* __restrict__ vb, bf16* __restrict__ Vt, int M)
{
    __shared__ __align__(16) bf16 lA[128 * 64];
    __shared__ __align__(16) bf16 lB[128 * 64];

    int x, yy;
    map_block(xcd_chunk(blockIdx.x, 77), 8, x, yy);
    const int m0 = x * 128, n0 = yy * 128;

    f32x4 acc[4][4] = {};
    gemm_core(A, Wv, M, m0, n0, acc, lA, lB);

    const int tid  = threadIdx.x;
    const int wave = tid >> 6, lane = tid & 63;
    const int ln   = lane & 15, lq = lane >> 4;
    const int wm = (wave & 1) * 64,  wn = (wave >> 1) * 64;

    const int hd0 = n0 + wn;                    // multiple of 64
    #pragma unroll
    for (int mi = 0; mi < 4; ++mi) {
        int trow = m0 + wm + mi * 16 + lq * 4;
        if (trow >= M) continue;
        #pragma unroll
        for (int ni = 0; ni < 4; ++ni) {
            int d = ni * 16 + ln;
            float bv = (float)vb[hd0 + d];
            bf16x4 o;
            #pragma unroll
            for (int r = 0; r < 4; ++r) o[r] = (bf16)(acc[mi][ni][r] + bv);
            *(bf16x4*)&Vt[(size_t)(hd0 + d) * T_TOTAL + trow] = o;
        }
    }
}

// ---------------------------------------------------------------------------
// Out-proj GEMM: writes d_out directly (fp32 or bf16 per disc). Grid 77*8.
// ---------------------------------------------------------------------------
__global__ __launch_bounds__(256, 2)
void gemm_out(const bf16* __restrict__ A, const bf16* __restrict__ W,
              const bf16* __restrict__ bias, void* __restrict__ out, int M,
              const unsigned short* __restrict__ disc)
{
    __shared__ __align__(16) bf16 lA[128 * 64];
    __shared__ __align__(16) bf16 lB[128 * 64];

    int x, yy;
    map_block(xcd_chunk(blockIdx.x, 77), 8, x, yy);
    const int m0 = x * 128, n0 = yy * 128;

    f32x4 acc[4][4] = {};
    gemm_core(A, W, M, m0, n0, acc, lA, lB);

    const bool f32 = (disc[0] == 0);
    const int tid  = threadIdx.x;
    const int wave = tid >> 6, lane = tid & 63;
    const int ln   = lane & 15, lq = lane >> 4;
    const int wm = (wave & 1) * 64,  wn = (wave >> 1) * 64;

    #pragma unroll
    for (int mi = 0; mi < 4; ++mi) {
        int trow = m0 + wm + mi * 16 + lq * 4;
        if (trow >= M) continue;
        #pragma unroll
        for (int ni = 0; ni < 4; ++ni) {
            int col = n0 + wn + ni * 16 + ln;
            float bv = (float)bias[col];
            #pragma unroll
            for (int r = 0; r < 4; ++r) {
                float v = acc[mi][ni][r] + bv;
                size_t idx = (size_t)(trow + r) * EMBED + col;
                if (f32) ((float*)out)[idx] = v;
                else     ((bf16*)out)[idx]  = (bf16)v;
            }
        }
    }
}

// ---------------------------------------------------------------------------
// Flash attention, S^T formulation. QBLK=128, 8 waves (verified R6).
// R7: LPT ordering — qx reversed within each head so the longest causal
// tiles schedule first (kills end-of-kernel straggler).
// Grid 77*16 = 1232 = 8*154 (XCD-chunked: 2 heads per XCD).
// ---------------------------------------------------------------------------
__global__ __launch_bounds__(512, 6)
void attn_kernel(const bf16* __restrict__ Q, const bf16* __restrict__ K,
                 const bf16* __restrict__ Vt, bf16* __restrict__ O)
{
    __shared__ __align__(16) bf16 sK[2][64 * 64];
    __shared__ __align__(16) bf16 sV[2][64 * 64];       // Vt tile: [dh][kv]
    __shared__ __align__(16) bf16 sQP[8 * 16 * 72];     // Q tile (128x64), later per-wave P

    const int tid  = threadIdx.x;
    const int wave = tid >> 6, lane = tid & 63;
    const int lrow = lane >> 3;
    const int gsw  = (lane & 7) ^ lrow;
    const int ln   = lane & 15, lq = lane >> 4;
    const int e7   = ln & 7;

    const int swz = xcd_chunk(blockIdx.x, 154);
    const int h  = swz / 77;
    const int qx = 76 - (swz - h * 77);                // LPT: big q-tiles first

    int b = 0;
    #pragma unroll
    for (int i = 1; i < 13; ++i) if (qx >= c_qtiles_cum[i]) b = i;
    const int qt   = qx - c_qtiles_cum[b];
    const int s0   = c_seq_start13[b];
    const int len  = c_seq_start13[b + 1] - s0;
    const int t0   = s0 + qt * 128;
    const int vrows = len - qt * 128;                  // 64 for half-tiles, else >=128
    const int lastrow = (vrows < 128 ? vrows : 128) - 1;
    const int jmax = (qt * 128 + lastrow) >> 6;        // 2qt+1 full, 2qt half

    // Q staging: rows t0..t0+127 (clamped at T end), swizzled granule.
    for (int p = 0; p < 2; ++p) {
        int r = p * 64 + wave * 8 + lrow;
        int qr = t0 + r; if (qr > T_TOTAL - 1) qr = T_TOTAL - 1;
        load_lds16(Q + (size_t)qr * EMBED + h * HDIM + gsw * 8, &sQP[r * 64]);
    }
    {
        int r = wave * 8 + lrow;                       // 8 waves cover 64 rows
        load_lds16(K  + (size_t)(s0 + r) * EMBED + h * HDIM + gsw * 8, &sK[0][r * 64]);
        load_lds16(Vt + (size_t)(h * HDIM + r) * T_TOTAL + s0 + gsw * 8, &sV[0][r * 64]);
    }

    bf16x8 qf[2];
    f32x4 oacc[4] = {};
    float m_i = -1e30f, l_i = 0.0f;
    const float sc = 0.125f * 1.44269504088896f;
    const int q_loc = wave * 16 + ln;                  // 0..127
    bf16* sP = &sQP[wave * 16 * 72];

    for (int j = 0; j <= jmax; ++j) {
        __syncthreads();
        const int cur = j & 1;
        if (j == 0) {
            qf[0] = *(const bf16x8*)&sQP[q_loc * 64 + ((0 + lq) ^ e7) * 8];
            qf[1] = *(const bf16x8*)&sQP[q_loc * 64 + ((4 + lq) ^ e7) * 8];
            __syncthreads();
        }
        if (j < jmax) {
            const int kvb = s0 + (j + 1) * 64;
            const int nxt = cur ^ 1;
            int r = wave * 8 + lrow;
            load_lds16(K  + (size_t)(kvb + r) * EMBED + h * HDIM + gsw * 8, &sK[nxt][r * 64]);
            load_lds16(Vt + (size_t)(h * HDIM + r) * T_TOTAL + kvb + gsw * 8, &sV[nxt][r * 64]);
        }

        f32x4 s[4] = {};
        #pragma unroll
        for (int kk = 0; kk < 2; ++kk)
            #pragma unroll
            for (int ni = 0; ni < 4; ++ni) {
                bf16x8 kf = *(const bf16x8*)&sK[cur][(ni * 16 + ln) * 64 + (((kk * 4 + lq) ^ e7) * 8)];
                s[ni] = mfma16(kf, qf[kk], s[ni]);      // S^T[kv][q]
            }

        float pb[4][4];
        if (j >= 2 * qt) {
            const int off = (j - 2 * qt) * 64;          // 0 or 64
            #pragma unroll
            for (int ni = 0; ni < 4; ++ni)
                #pragma unroll
                for (int r = 0; r < 4; ++r) {
                    int kv = off + ni * 16 + lq * 4 + r;
                    pb[ni][r] = (kv <= q_loc) ? s[ni][r] * sc : -1e30f;
                }
        } else {
            #pragma unroll
            for (int ni = 0; ni < 4; ++ni)
                #pragma unroll
                for (int r = 0; r < 4; ++r)
                    pb[ni][r] = s[ni][r] * sc;
        }

        float mx = pb[0][0];
        #pragma unroll
        for (int ni = 0; ni < 4; ++ni)
            #pragma unroll
            for (int r = 0; r < 4; ++r) mx = fmaxf(mx, pb[ni][r]);
        mx = fmaxf(mx, __shfl_xor(mx, 16));
        mx = fmaxf(mx, __shfl_xor(mx, 32));

        // T13 defer-max: only rescale when some row's max grew past m_i + 8.
        if (!__all(mx <= m_i + 8.0f)) {
            float mnew  = fmaxf(m_i, mx);
            float alpha = exp2f(m_i - mnew);
            l_i *= alpha;
            #pragma unroll
            for (int d = 0; d < 4; ++d)
                #pragma unroll
                for (int r = 0; r < 4; ++r) oacc[d][r] *= alpha;
            m_i = mnew;
        }

        float rs = 0.0f;
        #pragma unroll
        for (int ni = 0; ni < 4; ++ni)
            #pragma unroll
            for (int r = 0; r < 4; ++r) {
                float pe = exp2f(pb[ni][r] - m_i);
                pb[ni][r] = pe;
                rs += pe;
            }
        rs += __shfl_xor(rs, 16);
        rs += __shfl_xor(rs, 32);
        l_i += rs;

        #pragma unroll
        for (int ni = 0; ni < 4; ++ni) {
            bf16x4 w4;
            #pragma unroll
            for (int r = 0; r < 4; ++r) w4[r] = (bf16)pb[ni][r];
            *(bf16x4*)&sP[ln * 72 + ni * 16 + lq * 4] = w4;
        }
        asm volatile("s_waitcnt lgkmcnt(0)" ::: "memory");

        #pragma unroll
        for (int kk = 0; kk < 2; ++kk) {
            bf16x8 pf = *(const bf16x8*)&sP[ln * 72 + kk * 32 + lq * 8];
            #pragma unroll
            for (int d = 0; d < 4; ++d) {
                bf16x8 vf = *(const bf16x8*)&sV[cur][(d * 16 + ln) * 64 + (((kk * 4 + lq) ^ e7) * 8)];
                oacc[d] = mfma16(vf, pf, oacc[d]);      // O^T[dh][q]
            }
        }
    }

    if (q_loc < vrows) {
        const float inv = 1.0f / l_i;
        const size_t row = (size_t)(t0 + q_loc) * EMBED + h * HDIM;
        #pragma unroll
        for (int d = 0; d < 4; ++d) {
            bf16x4 o4;
            #pragma unroll
            for (int r = 0; r < 4; ++r) o4[r] = (bf16)(oacc[d][r] * inv);
            *(bf16x4*)&O[row + d * 16 + lq * 4] = o4;
        }
    }
}

// ---------------------------------------------------------------------------
extern "C" void kernel_launch(void* const* d_in, const int* in_sizes, int n_in,
                              void* d_out, int out_size, void* d_ws, size_t ws_size,
                              hipStream_t stream)
{
    const unsigned short* disc = (const unsigned short*)d_in[1];  // cos[0][0]

    const size_t SZ  = (size_t)T_TOTAL * EMBED;   // 10,027,008
    const size_t CS  = (size_t)T_TOTAL * HDIM;    // 626,688
    const size_t WSZ = (size_t)EMBED * EMBED;     // 1,048,576

    bf16* p = (bf16*)d_ws;
    bf16* ch   = p; p += SZ;
    bf16* ccos = p; p += CS;
    bf16* csin = p; p += CS;
    bf16* cqw  = p; p += WSZ;
    bf16* ckw  = p; p += WSZ;
    bf16* cvw  = p; p += WSZ;
    bf16* cow  = p; p += WSZ;
    bf16* cqb  = p; p += EMBED;
    bf16* cvb  = p; p += EMBED;
    bf16* cob  = p; p += EMBED;
    bf16* wq   = p; p += SZ;      // Q (post-RoPE), then attention output (in place)
    bf16* wk   = p; p += SZ;
    bf16* wvt  = p; p += SZ;      // V^T per head

    // Host-side dtype fast path: if inputs are already bf16 (byte sizes
    // match bf16), skip the conversion dispatch and read d_in directly.
    const bool all_bf16 =
        in_sizes[0] == (int)(SZ * 2)  && in_sizes[1] == (int)(CS * 2) &&
        in_sizes[2] == (int)(CS * 2)  && in_sizes[3] == (int)(WSZ * 2) &&
        in_sizes[5] == (int)(WSZ * 2) && in_sizes[6] == (int)(WSZ * 2) &&
        in_sizes[8] == (int)(WSZ * 2) && in_sizes[4] == (int)(EMBED * 2) &&
        in_sizes[7] == (int)(EMBED * 2) && in_sizes[9] == (int)(EMBED * 2);

    if (all_bf16) {
        ch   = (bf16*)d_in[0]; ccos = (bf16*)d_in[1]; csin = (bf16*)d_in[2];
        cqw  = (bf16*)d_in[3]; ckw  = (bf16*)d_in[5]; cvw  = (bf16*)d_in[6];
        cow  = (bf16*)d_in[8]; cqb  = (bf16*)d_in[4]; cvb  = (bf16*)d_in[7];
        cob  = (bf16*)d_in[9];
    } else {
        CvtArgs ca;
        const void* srcs[10] = {d_in[0], d_in[1], d_in[2], d_in[3], d_in[5],
                                d_in[6], d_in[8], d_in[4], d_in[7], d_in[9]};
        bf16* dsts[10] = {ch, ccos, csin, cqw, ckw, cvw, cow, cqb, cvb, cob};
        int   ns[10]   = {(int)SZ, (int)CS, (int)CS, (int)WSZ, (int)WSZ,
                          (int)WSZ, (int)WSZ, EMBED, EMBED, EMBED};
        int cum = 0;
        for (int i = 0; i < 10; ++i) {
            ca.src[i] = srcs[i]; ca.dst[i] = dsts[i]; ca.n[i] = ns[i];
            ca.cum[i] = cum;
            cum += (ns[i] + 2047) / 2048;
        }
        to_bf16_fused<<<cum, 256, 0, stream>>>(ca, disc);
    }

    gemm_qk<<<77 * 16, 256, 0, stream>>>(ch, cqw, ckw, cqb, ccos, csin,
                                         wq, wk, T_TOTAL);
    gemm_v<<<77 * 8, 256, 0, stream>>>(ch, cvw, cvb, wvt, T_TOTAL);
    attn_kernel<<<1232, 512, 0, stream>>>(wq, wk, wvt, wq);
    gemm_out<<<77 * 8, 256, 0, stream>>>(wq, cow, cob, d_out, T_TOTAL, disc);
}

// Round 8
// 284.808 us; speedup vs baseline: 1.0666x; 1.0666x over previous
//
#include <hip/hip_runtime.h>

typedef __bf16 bf16;
typedef __bf16 bf16x8 __attribute__((ext_vector_type(8)));
typedef __bf16 bf16x4 __attribute__((ext_vector_type(4)));
typedef float  f32x4  __attribute__((ext_vector_type(4)));

#define T_TOTAL 9792
#define EMBED   1024
#define NHEAD   16
#define HDIM    64

// Fixed problem geometry (LENGTHS are compile-time constants of this problem).
__constant__ int c_seq_start13[13] = {0,1024,1792,2688,3200,4224,4864,5888,6656,7168,8064,9088,9792};
// 128-row q-tiles per seq: [8,6,7,4,8,5,8,6,4,7,8,6] -> cumsum
__constant__ int c_qtiles_cum[13] = {0,8,14,21,25,33,38,46,52,56,63,71,77};

typedef __attribute__((address_space(1))) unsigned int gu32;
typedef __attribute__((address_space(3))) unsigned int lu32;

__device__ __forceinline__ void load_lds16(const void* g, void* l) {
    __builtin_amdgcn_global_load_lds((gu32*)g, (lu32*)l, 16, 0, 0);
}

__device__ __forceinline__ f32x4 mfma16(bf16x8 a, bf16x8 b, f32x4 c) {
    return __builtin_amdgcn_mfma_f32_16x16x32_bf16(a, b, c, 0, 0, 0);
}

// XCD-chunked remap (T1). MI355X: 8 XCDs, consecutive blockIdx round-robins
// XCDs; nwg%8==0 for all our grids -> bijective contiguous chunks per XCD.
__device__ __forceinline__ int xcd_chunk(int bid, int chunk) {
    return (bid & 7) * chunk + (bid >> 3);
}

// ---------------------------------------------------------------------------
// Fused dtype canonicalization: all 10 tensors in one dispatch.
// Discriminator: cos[0][0]==1.0 exactly -> fp32 first u16 is 0x0000.
// ---------------------------------------------------------------------------
struct CvtArgs {
    const void* src[10];
    bf16*       dst[10];
    int         n[10];
    int         cum[10];   // block offset of each segment
};

__global__ void to_bf16_fused(CvtArgs a, const unsigned short* __restrict__ disc)
{
    const bool f32 = (disc[0] == 0);
    const int blk = blockIdx.x;
    int seg = 0;
    #pragma unroll
    for (int i = 1; i < 10; ++i) if (blk >= a.cum[i]) seg = i;
    int i0 = (blk - a.cum[seg]) * 2048 + threadIdx.x * 8;
    if (i0 >= a.n[seg]) return;
    bf16x8 o;
    if (f32) {
        const float4* s = (const float4*)((const float*)a.src[seg] + i0);
        float4 x = s[0], y = s[1];
        o[0]=(bf16)x.x; o[1]=(bf16)x.y; o[2]=(bf16)x.z; o[3]=(bf16)x.w;
        o[4]=(bf16)y.x; o[5]=(bf16)y.y; o[6]=(bf16)y.z; o[7]=(bf16)y.w;
    } else {
        o = *(const bf16x8*)((const bf16*)a.src[seg] + i0);
    }
    *(bf16x8*)(a.dst[seg] + i0) = o;
}

// ---------------------------------------------------------------------------
// Shared GEMM core: acc = A[m0:+128] @ W[n0:+128]^T  (K=1024, BK=64).
// R4-verified structure (77 us, 0 bank conflicts): single 2x128x64 LDS,
// XOR-swizzled on the GLOBAL side of staging, 2 blocks/CU. FROZEN
// (scheduling experiments R1/R2/R3/R5 all regressed vs this).
// ---------------------------------------------------------------------------
__device__ __forceinline__
void gemm_core(const bf16* __restrict__ A, const bf16* __restrict__ W,
               int M, int m0, int n0, f32x4 (&acc)[4][4],
               bf16* lA, bf16* lB)
{
    const int tid  = threadIdx.x;
    const int wave = tid >> 6, lane = tid & 63;
    const int lrow = lane >> 3;
    const int gsw  = (lane & 7) ^ lrow;
    const int ln   = lane & 15, lq = lane >> 4;
    const int e7   = ln & 7;
    const int wm = (wave & 1) * 64,  wn = (wave >> 1) * 64;

    for (int k0 = 0; k0 < 1024; k0 += 64) {
        __syncthreads();
        for (int j = 0; j < 4; ++j) {
            int r = j * 32 + wave * 8;
            int gr = m0 + r + lrow; if (gr > M - 1) gr = M - 1;
            load_lds16(A + (size_t)gr * EMBED + k0 + gsw * 8, &lA[r * 64]);
            load_lds16(W + (size_t)(n0 + r + lrow) * EMBED + k0 + gsw * 8, &lB[r * 64]);
        }
        __syncthreads();
        #pragma unroll
        for (int kb = 0; kb < 2; ++kb) {
            bf16x8 af[4], bfr[4];
            #pragma unroll
            for (int i = 0; i < 4; ++i)
                af[i]  = *(const bf16x8*)&lA[(wm + i * 16 + ln) * 64 + (((kb * 4 + lq) ^ e7) * 8)];
            #pragma unroll
            for (int i = 0; i < 4; ++i)
                bfr[i] = *(const bf16x8*)&lB[(wn + i * 16 + ln) * 64 + (((kb * 4 + lq) ^ e7) * 8)];
            #pragma unroll
            for (int mi = 0; mi < 4; ++mi)
                #pragma unroll
                for (int ni = 0; ni < 4; ++ni)
                    acc[mi][ni] = mfma16(af[mi], bfr[ni], acc[mi][ni]);
        }
    }
}

// Supertile block map: 8 x-tiles per super-column x all NY, L2/L3 locality.
__device__ __forceinline__ void map_block(int L, int NY, int& x, int& y)
{
    const int per = 8 * NY;
    const int full = 9 * per;          // 72 of 77 x-tiles in full supercols
    if (L < full) { int sc = L / per, rem = L % per; x = sc * 8 + (rem & 7); y = rem >> 3; }
    else          { int rem = L - full; x = 72 + rem % 5; y = rem / 5; }
}

// ---------------------------------------------------------------------------
// QKV fused GEMM. 1D grid 77*24 (=8*231, XCD-chunked). which = y>>3.
// Epilogue: bias add, RoPE (Q,K on fp32 acc), V transpose -> Vt.
// R8: Q outputs pre-scaled by 0.125*log2(e) so attn skips the scale mul.
// ---------------------------------------------------------------------------
__global__ __launch_bounds__(256, 2)
void gemm_qkv(const bf16* __restrict__ A,
              const bf16* __restrict__ Wq, const bf16* __restrict__ Wk,
              const bf16* __restrict__ Wv, const bf16* __restrict__ qb,
              const bf16* __restrict__ vb,
              const bf16* __restrict__ cosb, const bf16* __restrict__ sinb,
              bf16* __restrict__ Cq, bf16* __restrict__ Ck,
              bf16* __restrict__ Vt, int M)
{
    __shared__ __align__(16) bf16 lA[128 * 64];
    __shared__ __align__(16) bf16 lB[128 * 64];

    int x, yy;
    map_block(xcd_chunk(blockIdx.x, 231), 24, x, yy);
    const int which = yy >> 3;
    const int m0 = x * 128, n0 = (yy & 7) * 128;

    const bf16* W = (which == 0) ? Wq : (which == 1) ? Wk : Wv;
    f32x4 acc[4][4] = {};
    gemm_core(A, W, M, m0, n0, acc, lA, lB);

    const int tid  = threadIdx.x;
    const int wave = tid >> 6, lane = tid & 63;
    const int ln   = lane & 15, lq = lane >> 4;
    const int wm = (wave & 1) * 64,  wn = (wave >> 1) * 64;

    if (which < 2) {
        // Q or K: bias (Q only) + RoPE on fp32 acc. Pair (d, d+32) = (ni, ni+2).
        bf16* C = (which == 0) ? Cq : Ck;
        const bf16* bias = (which == 0) ? qb : nullptr;
        const float post = (which == 0) ? 0.125f * 1.44269504088896f : 1.0f;
        #pragma unroll
        for (int mi = 0; mi < 4; ++mi) {
            int trow = m0 + wm + mi * 16 + lq * 4;
            if (trow >= M) continue;
            #pragma unroll
            for (int ni = 0; ni < 2; ++ni) {
                int d    = ni * 16 + ln;           // in [0,32)
                int col0 = n0 + wn + d;
                int col1 = col0 + 32;
                float b0 = bias ? (float)bias[col0] : 0.0f;
                float b1 = bias ? (float)bias[col1] : 0.0f;
                #pragma unroll
                for (int r = 0; r < 4; ++r) {
                    int t = trow + r;
                    float c = (float)cosb[t * HDIM + d];
                    float s = (float)sinb[t * HDIM + d];
                    float x0 = acc[mi][ni][r] + b0;
                    float x1 = acc[mi][ni + 2][r] + b1;
                    C[(size_t)t * EMBED + col0] = (bf16)((x0 * c - x1 * s) * post);
                    C[(size_t)t * EMBED + col1] = (bf16)((x1 * c + x0 * s) * post);
                }
            }
        }
    } else {
        // V: bias + direct transposed store Vt[(h*64+d) * T + t] (8B per (mi,ni))
        const int hd0 = n0 + wn;                    // multiple of 64
        #pragma unroll
        for (int mi = 0; mi < 4; ++mi) {
            int trow = m0 + wm + mi * 16 + lq * 4;
            if (trow >= M) continue;
            #pragma unroll
            for (int ni = 0; ni < 4; ++ni) {
                int d = ni * 16 + ln;
                float bv = (float)vb[hd0 + d];
                bf16x4 o;
                #pragma unroll
                for (int r = 0; r < 4; ++r) o[r] = (bf16)(acc[mi][ni][r] + bv);
                *(bf16x4*)&Vt[(size_t)(hd0 + d) * T_TOTAL + trow] = o;
            }
        }
    }
}

// ---------------------------------------------------------------------------
// Out-proj GEMM: writes d_out directly (fp32 or bf16 per disc). Grid 77*8.
// ---------------------------------------------------------------------------
__global__ __launch_bounds__(256, 2)
void gemm_out(const bf16* __restrict__ A, const bf16* __restrict__ W,
              const bf16* __restrict__ bias, void* __restrict__ out, int M,
              const unsigned short* __restrict__ disc)
{
    __shared__ __align__(16) bf16 lA[128 * 64];
    __shared__ __align__(16) bf16 lB[128 * 64];

    int x, yy;
    map_block(xcd_chunk(blockIdx.x, 77), 8, x, yy);
    const int m0 = x * 128, n0 = yy * 128;

    f32x4 acc[4][4] = {};
    gemm_core(A, W, M, m0, n0, acc, lA, lB);

    const bool f32 = (disc[0] == 0);
    const int tid  = threadIdx.x;
    const int wave = tid >> 6, lane = tid & 63;
    const int ln   = lane & 15, lq = lane >> 4;
    const int wm = (wave & 1) * 64,  wn = (wave >> 1) * 64;

    #pragma unroll
    for (int mi = 0; mi < 4; ++mi) {
        int trow = m0 + wm + mi * 16 + lq * 4;
        if (trow >= M) continue;
        #pragma unroll
        for (int ni = 0; ni < 4; ++ni) {
            int col = n0 + wn + ni * 16 + ln;
            float bv = (float)bias[col];
            #pragma unroll
            for (int r = 0; r < 4; ++r) {
                float v = acc[mi][ni][r] + bv;
                size_t idx = (size_t)(trow + r) * EMBED + col;
                if (f32) ((float*)out)[idx] = v;
                else     ((bf16*)out)[idx]  = (bf16)v;
            }
        }
    }
}

// ---------------------------------------------------------------------------
// Flash attention, S^T formulation. QBLK=128, 8 waves (R6-verified geometry).
// R8 changes (core math untouched):
//  - Q fragments loaded DIRECT from global to registers (content proven
//    identical to the staged+swizzled read) -> no Q staging, no j==0
//    double-barrier, sQP is now pure per-wave P storage.
//  - Softmax row-SUM via MFMA ones-trick: l_acc = mfma(ones, pf, l_acc);
//    D[row][col] = sum_k P^T[k][col] (all rows equal). Replaces 16 VALU adds
//    + 2 LDS-pipe shfls per iter with 2 MFMAs on the 10%-utilized pipe, and
//    makes l consistent with the bf16 P used for PV.
//  - Q pre-scaled by 0.125*log2e in gemm_qkv -> no scale mul here.
//  - max-reduce tree nested for v_max3 fusion.
// Grid 77*16 = 1232 = 8*154 (XCD-chunked: 2 heads per XCD, K/V L2-resident).
// ---------------------------------------------------------------------------
__global__ __launch_bounds__(512, 6)
void attn_kernel(const bf16* __restrict__ Q, const bf16* __restrict__ K,
                 const bf16* __restrict__ Vt, bf16* __restrict__ O)
{
    __shared__ __align__(16) bf16 sK[2][64 * 64];
    __shared__ __align__(16) bf16 sV[2][64 * 64];       // Vt tile: [dh][kv]
    __shared__ __align__(16) bf16 sP[8][16 * 72];       // per-wave P

    const int tid  = threadIdx.x;
    const int wave = tid >> 6, lane = tid & 63;
    const int lrow = lane >> 3;
    const int gsw  = (lane & 7) ^ lrow;
    const int ln   = lane & 15, lq = lane >> 4;
    const int e7   = ln & 7;

    const int swz = xcd_chunk(blockIdx.x, 154);
    const int h  = swz / 77;
    const int qx = swz - h * 77;

    int b = 0;
    #pragma unroll
    for (int i = 1; i < 13; ++i) if (qx >= c_qtiles_cum[i]) b = i;
    const int qt   = qx - c_qtiles_cum[b];
    const int s0   = c_seq_start13[b];
    const int len  = c_seq_start13[b + 1] - s0;
    const int t0   = s0 + qt * 128;
    const int vrows = len - qt * 128;                  // 64 for the one half-tile
    const int lastrow = (vrows < 128 ? vrows : 128) - 1;
    const int jmax = (qt * 128 + lastrow) >> 6;

    // K/V tile 0 staging (swizzled-source, linear LDS dest).
    {
        int r = wave * 8 + lrow;                       // 8 waves cover 64 rows
        load_lds16(K  + (size_t)(s0 + r) * EMBED + h * HDIM + gsw * 8, &sK[0][r * 64]);
        load_lds16(Vt + (size_t)(h * HDIM + r) * T_TOTAL + s0 + gsw * 8, &sV[0][r * 64]);
    }

    // Q fragments direct from global (row t0+q_loc, 2x16B contiguous).
    const int q_loc = wave * 16 + ln;                  // 0..127
    int qrow = t0 + q_loc; if (qrow > T_TOTAL - 1) qrow = T_TOTAL - 1;
    bf16x8 qf[2];
    qf[0] = *(const bf16x8*)&Q[(size_t)qrow * EMBED + h * HDIM + lq * 8];
    qf[1] = *(const bf16x8*)&Q[(size_t)qrow * EMBED + h * HDIM + 32 + lq * 8];

    bf16x8 ones;
    #pragma unroll
    for (int i = 0; i < 8; ++i) ones[i] = (bf16)1.0f;

    f32x4 oacc[4] = {};
    f32x4 l_acc = {};
    float m_i = -1e30f;
    bf16* myP = &sP[wave][0];

    for (int j = 0; j <= jmax; ++j) {
        __syncthreads();
        const int cur = j & 1;
        if (j < jmax) {
            const int kvb = s0 + (j + 1) * 64;
            const int nxt = cur ^ 1;
            int r = wave * 8 + lrow;
            load_lds16(K  + (size_t)(kvb + r) * EMBED + h * HDIM + gsw * 8, &sK[nxt][r * 64]);
            load_lds16(Vt + (size_t)(h * HDIM + r) * T_TOTAL + kvb + gsw * 8, &sV[nxt][r * 64]);
        }

        f32x4 s[4] = {};
        #pragma unroll
        for (int kk = 0; kk < 2; ++kk)
            #pragma unroll
            for (int ni = 0; ni < 4; ++ni) {
                bf16x8 kf = *(const bf16x8*)&sK[cur][(ni * 16 + ln) * 64 + (((kk * 4 + lq) ^ e7) * 8)];
                s[ni] = mfma16(kf, qf[kk], s[ni]);      // S^T[kv][q], pre-scaled
            }

        float pb[4][4];
        if (j >= 2 * qt) {
            const int off = (j - 2 * qt) * 64;          // 0 or 64
            #pragma unroll
            for (int ni = 0; ni < 4; ++ni)
                #pragma unroll
                for (int r = 0; r < 4; ++r) {
                    int kv = off + ni * 16 + lq * 4 + r;
                    pb[ni][r] = (kv <= q_loc) ? s[ni][r] : -1e30f;
                }
        } else {
            #pragma unroll
            for (int ni = 0; ni < 4; ++ni)
                #pragma unroll
                for (int r = 0; r < 4; ++r)
                    pb[ni][r] = s[ni][r];
        }

        // max tree (v_max3-friendly) + 2 cross-lane combines (4 lq lanes/row).
        float a0 = fmaxf(fmaxf(pb[0][0], pb[0][1]), pb[0][2]);
        float a1 = fmaxf(fmaxf(pb[0][3], pb[1][0]), pb[1][1]);
        float a2 = fmaxf(fmaxf(pb[1][2], pb[1][3]), pb[2][0]);
        float a3 = fmaxf(fmaxf(pb[2][1], pb[2][2]), pb[2][3]);
        float a4 = fmaxf(fmaxf(pb[3][0], pb[3][1]), pb[3][2]);
        float mx = fmaxf(fmaxf(fmaxf(a0, a1), fmaxf(a2, a3)), fmaxf(a4, pb[3][3]));
        mx = fmaxf(mx, __shfl_xor(mx, 16));
        mx = fmaxf(mx, __shfl_xor(mx, 32));

        // T13 defer-max: rescale only when some row's max grew past m_i + 8.
        if (!__all(mx <= m_i + 8.0f)) {
            float mnew  = fmaxf(m_i, mx);
            float alpha = exp2f(m_i - mnew);
            #pragma unroll
            for (int r = 0; r < 4; ++r) l_acc[r] *= alpha;
            #pragma unroll
            for (int d = 0; d < 4; ++d)
                #pragma unroll
                for (int r = 0; r < 4; ++r) oacc[d][r] *= alpha;
            m_i = mnew;
        }

        #pragma unroll
        for (int ni = 0; ni < 4; ++ni) {
            bf16x4 w4;
            #pragma unroll
            for (int r = 0; r < 4; ++r) w4[r] = (bf16)exp2f(pb[ni][r] - m_i);
            *(bf16x4*)&myP[ln * 72 + ni * 16 + lq * 4] = w4;
        }
        asm volatile("s_waitcnt lgkmcnt(0)" ::: "memory");

        #pragma unroll
        for (int kk = 0; kk < 2; ++kk) {
            bf16x8 pf = *(const bf16x8*)&myP[ln * 72 + kk * 32 + lq * 8];
            l_acc = mfma16(ones, pf, l_acc);            // row-sum on MFMA pipe
            #pragma unroll
            for (int d = 0; d < 4; ++d) {
                bf16x8 vf = *(const bf16x8*)&sV[cur][(d * 16 + ln) * 64 + (((kk * 4 + lq) ^ e7) * 8)];
                oacc[d] = mfma16(vf, pf, oacc[d]);      // O^T[dh][q]
            }
        }
    }

    if (q_loc < vrows) {
        const float inv = 1.0f / l_acc[0];
        const size_t row = (size_t)(t0 + q_loc) * EMBED + h * HDIM;
        #pragma unroll
        for (int d = 0; d < 4; ++d) {
            bf16x4 o4;
            #pragma unroll
            for (int r = 0; r < 4; ++r) o4[r] = (bf16)(oacc[d][r] * inv);
            *(bf16x4*)&O[row + d * 16 + lq * 4] = o4;
        }
    }
}

// ---------------------------------------------------------------------------
extern "C" void kernel_launch(void* const* d_in, const int* in_sizes, int n_in,
                              void* d_out, int out_size, void* d_ws, size_t ws_size,
                              hipStream_t stream)
{
    const unsigned short* disc = (const unsigned short*)d_in[1];  // cos[0][0]

    const size_t SZ  = (size_t)T_TOTAL * EMBED;   // 10,027,008
    const size_t CS  = (size_t)T_TOTAL * HDIM;    // 626,688
    const size_t WSZ = (size_t)EMBED * EMBED;     // 1,048,576

    bf16* p = (bf16*)d_ws;
    bf16* ch   = p; p += SZ;
    bf16* ccos = p; p += CS;
    bf16* csin = p; p += CS;
    bf16* cqw  = p; p += WSZ;
    bf16* ckw  = p; p += WSZ;
    bf16* cvw  = p; p += WSZ;
    bf16* cow  = p; p += WSZ;
    bf16* cqb  = p; p += EMBED;
    bf16* cvb  = p; p += EMBED;
    bf16* cob  = p; p += EMBED;
    bf16* wq   = p; p += SZ;      // Q (post-RoPE, pre-scaled), then attn out
    bf16* wk   = p; p += SZ;
    bf16* wvt  = p; p += SZ;      // V^T per head

    CvtArgs ca;
    const void* srcs[10] = {d_in[0], d_in[1], d_in[2], d_in[3], d_in[5],
                            d_in[6], d_in[8], d_in[4], d_in[7], d_in[9]};
    bf16* dsts[10] = {ch, ccos, csin, cqw, ckw, cvw, cow, cqb, cvb, cob};
    int   ns[10]   = {(int)SZ, (int)CS, (int)CS, (int)WSZ, (int)WSZ,
                      (int)WSZ, (int)WSZ, EMBED, EMBED, EMBED};
    int cum = 0;
    for (int i = 0; i < 10; ++i) {
        ca.src[i] = srcs[i]; ca.dst[i] = dsts[i]; ca.n[i] = ns[i];
        ca.cum[i] = cum;
        cum += (ns[i] + 2047) / 2048;
    }
    to_bf16_fused<<<cum, 256, 0, stream>>>(ca, disc);

    gemm_qkv<<<77 * 24, 256, 0, stream>>>(ch, cqw, ckw, cvw, cqb, cvb,
                                          ccos, csin, wq, wk, wvt, T_TOTAL);
    attn_kernel<<<1232, 512, 0, stream>>>(wq, wk, wvt, wq);
    gemm_out<<<77 * 8, 256, 0, stream>>>(wq, cow, cob, d_out, T_TOTAL, disc);
}

// Round 9
// 278.080 us; speedup vs baseline: 1.0924x; 1.0242x over previous
//
#include <hip/hip_runtime.h>

typedef __bf16 bf16;
typedef __bf16 bf16x8 __attribute__((ext_vector_type(8)));
typedef __bf16 bf16x4 __attribute__((ext_vector_type(4)));
typedef float  f32x4  __attribute__((ext_vector_type(4)));

#define T_TOTAL 9792
#define EMBED   1024
#define NHEAD   16
#define HDIM    64

// Fixed problem geometry (LENGTHS are compile-time constants of this problem).
__constant__ int c_seq_start13[13] = {0,1024,1792,2688,3200,4224,4864,5888,6656,7168,8064,9088,9792};
// 128-row q-tiles per seq: [8,6,7,4,8,5,8,6,4,7,8,6] -> cumsum
__constant__ int c_qtiles_cum[13] = {0,8,14,21,25,33,38,46,52,56,63,71,77};

typedef __attribute__((address_space(1))) unsigned int gu32;
typedef __attribute__((address_space(3))) unsigned int lu32;

__device__ __forceinline__ void load_lds16(const void* g, void* l) {
    __builtin_amdgcn_global_load_lds((gu32*)g, (lu32*)l, 16, 0, 0);
}

__device__ __forceinline__ f32x4 mfma16(bf16x8 a, bf16x8 b, f32x4 c) {
    return __builtin_amdgcn_mfma_f32_16x16x32_bf16(a, b, c, 0, 0, 0);
}

__device__ __forceinline__ unsigned int cvtpk_bf16(float lo, float hi) {
    unsigned int r;
    asm("v_cvt_pk_bf16_f32 %0, %1, %2" : "=v"(r) : "v"(lo), "v"(hi));
    return r;
}

// XCD-chunked remap (T1). MI355X: 8 XCDs, consecutive blockIdx round-robins
// XCDs; nwg%8==0 for all our grids -> bijective contiguous chunks per XCD.
__device__ __forceinline__ int xcd_chunk(int bid, int chunk) {
    return (bid & 7) * chunk + (bid >> 3);
}

// ---------------------------------------------------------------------------
// Fused dtype canonicalization: all 10 tensors in one dispatch.
// Discriminator: cos[0][0]==1.0 exactly -> fp32 first u16 is 0x0000.
// ---------------------------------------------------------------------------
struct CvtArgs {
    const void* src[10];
    bf16*       dst[10];
    int         n[10];
    int         cum[10];   // block offset of each segment
};

__global__ void to_bf16_fused(CvtArgs a, const unsigned short* __restrict__ disc)
{
    const bool f32 = (disc[0] == 0);
    const int blk = blockIdx.x;
    int seg = 0;
    #pragma unroll
    for (int i = 1; i < 10; ++i) if (blk >= a.cum[i]) seg = i;
    int i0 = (blk - a.cum[seg]) * 2048 + threadIdx.x * 8;
    if (i0 >= a.n[seg]) return;
    bf16x8 o;
    if (f32) {
        const float4* s = (const float4*)((const float*)a.src[seg] + i0);
        float4 x = s[0], y = s[1];
        o[0]=(bf16)x.x; o[1]=(bf16)x.y; o[2]=(bf16)x.z; o[3]=(bf16)x.w;
        o[4]=(bf16)y.x; o[5]=(bf16)y.y; o[6]=(bf16)y.z; o[7]=(bf16)y.w;
    } else {
        o = *(const bf16x8*)((const bf16*)a.src[seg] + i0);
    }
    *(bf16x8*)(a.dst[seg] + i0) = o;
}

// ---------------------------------------------------------------------------
// Shared GEMM core: acc = A[m0:+128] @ W[n0:+128]^T  (K=1024, BK=64).
// R4-verified structure (77 us, 0 bank conflicts): single 2x128x64 LDS,
// XOR-swizzled on the GLOBAL side of staging, 2 blocks/CU. FROZEN.
// ---------------------------------------------------------------------------
__device__ __forceinline__
void gemm_core(const bf16* __restrict__ A, const bf16* __restrict__ W,
               int M, int m0, int n0, f32x4 (&acc)[4][4],
               bf16* lA, bf16* lB)
{
    const int tid  = threadIdx.x;
    const int wave = tid >> 6, lane = tid & 63;
    const int lrow = lane >> 3;
    const int gsw  = (lane & 7) ^ lrow;
    const int ln   = lane & 15, lq = lane >> 4;
    const int e7   = ln & 7;
    const int wm = (wave & 1) * 64,  wn = (wave >> 1) * 64;

    for (int k0 = 0; k0 < 1024; k0 += 64) {
        __syncthreads();
        for (int j = 0; j < 4; ++j) {
            int r = j * 32 + wave * 8;
            int gr = m0 + r + lrow; if (gr > M - 1) gr = M - 1;
            load_lds16(A + (size_t)gr * EMBED + k0 + gsw * 8, &lA[r * 64]);
            load_lds16(W + (size_t)(n0 + r + lrow) * EMBED + k0 + gsw * 8, &lB[r * 64]);
        }
        __syncthreads();
        #pragma unroll
        for (int kb = 0; kb < 2; ++kb) {
            bf16x8 af[4], bfr[4];
            #pragma unroll
            for (int i = 0; i < 4; ++i)
                af[i]  = *(const bf16x8*)&lA[(wm + i * 16 + ln) * 64 + (((kb * 4 + lq) ^ e7) * 8)];
            #pragma unroll
            for (int i = 0; i < 4; ++i)
                bfr[i] = *(const bf16x8*)&lB[(wn + i * 16 + ln) * 64 + (((kb * 4 + lq) ^ e7) * 8)];
            #pragma unroll
            for (int mi = 0; mi < 4; ++mi)
                #pragma unroll
                for (int ni = 0; ni < 4; ++ni)
                    acc[mi][ni] = mfma16(af[mi], bfr[ni], acc[mi][ni]);
        }
    }
}

// Supertile block map: 8 x-tiles per super-column x all NY, L2/L3 locality.
__device__ __forceinline__ void map_block(int L, int NY, int& x, int& y)
{
    const int per = 8 * NY;
    const int full = 9 * per;          // 72 of 77 x-tiles in full supercols
    if (L < full) { int sc = L / per, rem = L % per; x = sc * 8 + (rem & 7); y = rem >> 3; }
    else          { int rem = L - full; x = 72 + rem % 5; y = rem / 5; }
}

// ---------------------------------------------------------------------------
// QKV fused GEMM. 1D grid 77*24 (=8*231, XCD-chunked). which = y>>3.
// Epilogue: bias add, RoPE (Q,K on fp32 acc), V transpose -> Vt.
// Q outputs pre-scaled by 0.125*log2(e) so attn skips the scale mul.
// ---------------------------------------------------------------------------
__global__ __launch_bounds__(256, 2)
void gemm_qkv(const bf16* __restrict__ A,
              const bf16* __restrict__ Wq, const bf16* __restrict__ Wk,
              const bf16* __restrict__ Wv, const bf16* __restrict__ qb,
              const bf16* __restrict__ vb,
              const bf16* __restrict__ cosb, const bf16* __restrict__ sinb,
              bf16* __restrict__ Cq, bf16* __restrict__ Ck,
              bf16* __restrict__ Vt, int M)
{
    __shared__ __align__(16) bf16 lA[128 * 64];
    __shared__ __align__(16) bf16 lB[128 * 64];

    int x, yy;
    map_block(xcd_chunk(blockIdx.x, 231), 24, x, yy);
    const int which = yy >> 3;
    const int m0 = x * 128, n0 = (yy & 7) * 128;

    const bf16* W = (which == 0) ? Wq : (which == 1) ? Wk : Wv;
    f32x4 acc[4][4] = {};
    gemm_core(A, W, M, m0, n0, acc, lA, lB);

    const int tid  = threadIdx.x;
    const int wave = tid >> 6, lane = tid & 63;
    const int ln   = lane & 15, lq = lane >> 4;
    const int wm = (wave & 1) * 64,  wn = (wave >> 1) * 64;

    if (which < 2) {
        // Q or K: bias (Q only) + RoPE on fp32 acc. Pair (d, d+32) = (ni, ni+2).
        bf16* C = (which == 0) ? Cq : Ck;
        const bf16* bias = (which == 0) ? qb : nullptr;
        const float post = (which == 0) ? 0.125f * 1.44269504088896f : 1.0f;
        #pragma unroll
        for (int mi = 0; mi < 4; ++mi) {
            int trow = m0 + wm + mi * 16 + lq * 4;
            if (trow >= M) continue;
            #pragma unroll
            for (int ni = 0; ni < 2; ++ni) {
                int d    = ni * 16 + ln;           // in [0,32)
                int col0 = n0 + wn + d;
                int col1 = col0 + 32;
                float b0 = bias ? (float)bias[col0] : 0.0f;
                float b1 = bias ? (float)bias[col1] : 0.0f;
                #pragma unroll
                for (int r = 0; r < 4; ++r) {
                    int t = trow + r;
                    float c = (float)cosb[t * HDIM + d];
                    float s = (float)sinb[t * HDIM + d];
                    float x0 = acc[mi][ni][r] + b0;
                    float x1 = acc[mi][ni + 2][r] + b1;
                    C[(size_t)t * EMBED + col0] = (bf16)((x0 * c - x1 * s) * post);
                    C[(size_t)t * EMBED + col1] = (bf16)((x1 * c + x0 * s) * post);
                }
            }
        }
    } else {
        // V: bias + direct transposed store Vt[(h*64+d) * T + t] (8B per (mi,ni))
        const int hd0 = n0 + wn;                    // multiple of 64
        #pragma unroll
        for (int mi = 0; mi < 4; ++mi) {
            int trow = m0 + wm + mi * 16 + lq * 4;
            if (trow >= M) continue;
            #pragma unroll
            for (int ni = 0; ni < 4; ++ni) {
                int d = ni * 16 + ln;
                float bv = (float)vb[hd0 + d];
                bf16x4 o;
                #pragma unroll
                for (int r = 0; r < 4; ++r) o[r] = (bf16)(acc[mi][ni][r] + bv);
                *(bf16x4*)&Vt[(size_t)(hd0 + d) * T_TOTAL + trow] = o;
            }
        }
    }
}

// ---------------------------------------------------------------------------
// Out-proj GEMM: writes d_out directly (fp32 or bf16 per disc). Grid 77*8.
// ---------------------------------------------------------------------------
__global__ __launch_bounds__(256, 2)
void gemm_out(const bf16* __restrict__ A, const bf16* __restrict__ W,
              const bf16* __restrict__ bias, void* __restrict__ out, int M,
              const unsigned short* __restrict__ disc)
{
    __shared__ __align__(16) bf16 lA[128 * 64];
    __shared__ __align__(16) bf16 lB[128 * 64];

    int x, yy;
    map_block(xcd_chunk(blockIdx.x, 77), 8, x, yy);
    const int m0 = x * 128, n0 = yy * 128;

    f32x4 acc[4][4] = {};
    gemm_core(A, W, M, m0, n0, acc, lA, lB);

    const bool f32 = (disc[0] == 0);
    const int tid  = threadIdx.x;
    const int wave = tid >> 6, lane = tid & 63;
    const int ln   = lane & 15, lq = lane >> 4;
    const int wm = (wave & 1) * 64,  wn = (wave >> 1) * 64;

    #pragma unroll
    for (int mi = 0; mi < 4; ++mi) {
        int trow = m0 + wm + mi * 16 + lq * 4;
        if (trow >= M) continue;
        #pragma unroll
        for (int ni = 0; ni < 4; ++ni) {
            int col = n0 + wn + ni * 16 + ln;
            float bv = (float)bias[col];
            #pragma unroll
            for (int r = 0; r < 4; ++r) {
                float v = acc[mi][ni][r] + bv;
                size_t idx = (size_t)(trow + r) * EMBED + col;
                if (f32) ((float*)out)[idx] = v;
                else     ((bf16*)out)[idx]  = (bf16)v;
            }
        }
    }
}

// ---------------------------------------------------------------------------
// Flash attention, S^T formulation. QBLK=128, 8 waves.
// R9 (diagnosis: ~4800cy/iter = exposed K/V load latency at 1.5 blocks/CU):
//  - 3-deep K/V pipeline: stage(j+2) each iter; counted s_waitcnt vmcnt(2)
//    + raw s_barrier per iter (m201-verified counted pattern; no full drain
//    until the tail). Tile j's loads get two full compute bodies of cover.
//  - P kept in REGISTERS: 8 cvt_pk + 16 ds_bpermute route P^T fragments
//    directly into the PV B-operand layout (kv = kk*32+lq*8+j pulled from
//    lane (ln, (lq&1)*2+(j>>2)) reg [kk*2+(lq>>1)][j&3]). sP eliminated
//    (-18KB LDS, kills the 1.83M bank conflicts and the lgkmcnt(0) wait).
//  - cross-lane max shfls only inside the rare rescale branch (__all
//    wave-reduces the trigger).
//  - T5 setprio around both MFMA clusters. LPT ordering (R7).
// Grid 77*16 = 1232 = 8*154 (XCD-chunked: 2 heads per XCD).
// ---------------------------------------------------------------------------
__global__ __launch_bounds__(512, 6)
void attn_kernel(const bf16* __restrict__ Q, const bf16* __restrict__ K,
                 const bf16* __restrict__ Vt, bf16* __restrict__ O)
{
    __shared__ __align__(16) bf16 sK[3][64 * 64];
    __shared__ __align__(16) bf16 sV[3][64 * 64];       // Vt tile: [dh][kv]

    const int tid  = threadIdx.x;
    const int wave = tid >> 6, lane = tid & 63;
    const int lrow = lane >> 3;
    const int gsw  = (lane & 7) ^ lrow;
    const int ln   = lane & 15, lq = lane >> 4;
    const int e7   = ln & 7;

    const int swz = xcd_chunk(blockIdx.x, 154);
    const int h  = swz / 77;
    const int qx = 76 - (swz - h * 77);                // LPT: big q-tiles first

    int b = 0;
    #pragma unroll
    for (int i = 1; i < 13; ++i) if (qx >= c_qtiles_cum[i]) b = i;
    const int qt   = qx - c_qtiles_cum[b];
    const int s0   = c_seq_start13[b];
    const int len  = c_seq_start13[b + 1] - s0;
    const int t0   = s0 + qt * 128;
    const int vrows = len - qt * 128;                  // 64 for the one half-tile
    const int lastrow = (vrows < 128 ? vrows : 128) - 1;
    const int jmax = (qt * 128 + lastrow) >> 6;        // >= 1 always (len >= 512)

    // Q fragments direct from global first (oldest vmcnt entries, consumed at j=0).
    const int q_loc = wave * 16 + ln;                  // 0..127
    int qrow = t0 + q_loc; if (qrow > T_TOTAL - 1) qrow = T_TOTAL - 1;
    bf16x8 qf[2];
    qf[0] = *(const bf16x8*)&Q[(size_t)qrow * EMBED + h * HDIM + lq * 8];
    qf[1] = *(const bf16x8*)&Q[(size_t)qrow * EMBED + h * HDIM + 32 + lq * 8];

    // K/V staging: 2 loads per wave per tile (8 waves cover 64 rows).
    const int srow = wave * 8 + lrow;
    auto stage = [&](int j, int buf) {
        const int kvb = s0 + j * 64;
        load_lds16(K  + (size_t)(kvb + srow) * EMBED + h * HDIM + gsw * 8, &sK[buf][srow * 64]);
        load_lds16(Vt + (size_t)(h * HDIM + srow) * T_TOTAL + kvb + gsw * 8, &sV[buf][srow * 64]);
    };

    stage(0, 0);
    stage(1, 1);

    bf16x8 ones;
    #pragma unroll
    for (int i = 0; i < 8; ++i) ones[i] = (bf16)1.0f;

    f32x4 oacc[4] = {};
    f32x4 l_acc = {};
    float m_i = -1e30f;

    // bpermute routing (derivation in header comment; spot-checked lanes 0, 20).
    const int srcA = (lane & 15) | ((lane & 16) << 1);
    const int srcB = srcA + 16;
    const bool hiSel = (lane & 32) != 0;

    int cur = 0;
    for (int j = 0; j <= jmax; ++j) {
        if (j < jmax) asm volatile("s_waitcnt vmcnt(2)" ::: "memory");
        else          asm volatile("s_waitcnt vmcnt(0)" ::: "memory");
        asm volatile("s_barrier" ::: "memory");
        if (j + 2 <= jmax) {
            int nb = cur + 2; if (nb >= 3) nb -= 3;
            stage(j + 2, nb);
        }

        f32x4 s[4] = {};
        __builtin_amdgcn_s_setprio(1);
        #pragma unroll
        for (int kk = 0; kk < 2; ++kk)
            #pragma unroll
            for (int ni = 0; ni < 4; ++ni) {
                bf16x8 kf = *(const bf16x8*)&sK[cur][(ni * 16 + ln) * 64 + (((kk * 4 + lq) ^ e7) * 8)];
                s[ni] = mfma16(kf, qf[kk], s[ni]);      // S^T[kv][q], pre-scaled
            }
        __builtin_amdgcn_s_setprio(0);

        float pb[4][4];
        if (j >= 2 * qt) {
            const int off = (j - 2 * qt) * 64;          // 0 or 64
            #pragma unroll
            for (int ni = 0; ni < 4; ++ni)
                #pragma unroll
                for (int r = 0; r < 4; ++r) {
                    int kv = off + ni * 16 + lq * 4 + r;
                    pb[ni][r] = (kv <= q_loc) ? s[ni][r] : -1e30f;
                }
        } else {
            #pragma unroll
            for (int ni = 0; ni < 4; ++ni)
                #pragma unroll
                for (int r = 0; r < 4; ++r)
                    pb[ni][r] = s[ni][r];
        }

        // lane-local max; wave-reduce only when rescale triggers (__all covers wave).
        float a0 = fmaxf(fmaxf(pb[0][0], pb[0][1]), pb[0][2]);
        float a1 = fmaxf(fmaxf(pb[0][3], pb[1][0]), pb[1][1]);
        float a2 = fmaxf(fmaxf(pb[1][2], pb[1][3]), pb[2][0]);
        float a3 = fmaxf(fmaxf(pb[2][1], pb[2][2]), pb[2][3]);
        float a4 = fmaxf(fmaxf(pb[3][0], pb[3][1]), pb[3][2]);
        float mx = fmaxf(fmaxf(fmaxf(a0, a1), fmaxf(a2, a3)), fmaxf(a4, pb[3][3]));

        if (!__all(mx <= m_i + 8.0f)) {
            mx = fmaxf(mx, __shfl_xor(mx, 16));
            mx = fmaxf(mx, __shfl_xor(mx, 32));
            float mnew  = fmaxf(m_i, mx);
            float alpha = exp2f(m_i - mnew);
            #pragma unroll
            for (int r = 0; r < 4; ++r) l_acc[r] *= alpha;
            #pragma unroll
            for (int d = 0; d < 4; ++d)
                #pragma unroll
                for (int r = 0; r < 4; ++r) oacc[d][r] *= alpha;
            m_i = mnew;
        }

        // exp + pack: c[ni][h] = bf16pair(exp(pb[ni][2h]), exp(pb[ni][2h+1]))
        unsigned int c[4][2];
        #pragma unroll
        for (int ni = 0; ni < 4; ++ni) {
            float e0 = exp2f(pb[ni][0] - m_i), e1 = exp2f(pb[ni][1] - m_i);
            float e2 = exp2f(pb[ni][2] - m_i), e3 = exp2f(pb[ni][3] - m_i);
            c[ni][0] = cvtpk_bf16(e0, e1);
            c[ni][1] = cvtpk_bf16(e2, e3);
        }

        // route P^T into PV B-fragments (16 bpermute + 8 selects), then PV.
        __builtin_amdgcn_s_setprio(1);
        #pragma unroll
        for (int kk = 0; kk < 2; ++kk) {
            union { unsigned int u[4]; bf16x8 v; } pu;
            unsigned int aA0 = __shfl((int)c[kk*2][0], srcA), bA0 = __shfl((int)c[kk*2+1][0], srcA);
            unsigned int aA1 = __shfl((int)c[kk*2][1], srcA), bA1 = __shfl((int)c[kk*2+1][1], srcA);
            unsigned int aB0 = __shfl((int)c[kk*2][0], srcB), bB0 = __shfl((int)c[kk*2+1][0], srcB);
            unsigned int aB1 = __shfl((int)c[kk*2][1], srcB), bB1 = __shfl((int)c[kk*2+1][1], srcB);
            pu.u[0] = hiSel ? bA0 : aA0;
            pu.u[1] = hiSel ? bA1 : aA1;
            pu.u[2] = hiSel ? bB0 : aB0;
            pu.u[3] = hiSel ? bB1 : aB1;
            bf16x8 pf = pu.v;
            l_acc = mfma16(ones, pf, l_acc);            // row-sum on MFMA pipe
            #pragma unroll
            for (int d = 0; d < 4; ++d) {
                bf16x8 vf = *(const bf16x8*)&sV[cur][(d * 16 + ln) * 64 + (((kk * 4 + lq) ^ e7) * 8)];
                oacc[d] = mfma16(vf, pf, oacc[d]);      // O^T[dh][q]
            }
        }
        __builtin_amdgcn_s_setprio(0);

        ++cur; if (cur == 3) cur = 0;
    }

    if (q_loc < vrows) {
        const float inv = 1.0f / l_acc[0];
        const size_t row = (size_t)(t0 + q_loc) * EMBED + h * HDIM;
        #pragma unroll
        for (int d = 0; d < 4; ++d) {
            bf16x4 o4;
            #pragma unroll
            for (int r = 0; r < 4; ++r) o4[r] = (bf16)(oacc[d][r] * inv);
            *(bf16x4*)&O[row + d * 16 + lq * 4] = o4;
        }
    }
}

// ---------------------------------------------------------------------------
extern "C" void kernel_launch(void* const* d_in, const int* in_sizes, int n_in,
                              void* d_out, int out_size, void* d_ws, size_t ws_size,
                              hipStream_t stream)
{
    const unsigned short* disc = (const unsigned short*)d_in[1];  // cos[0][0]

    const size_t SZ  = (size_t)T_TOTAL * EMBED;   // 10,027,008
    const size_t CS  = (size_t)T_TOTAL * HDIM;    // 626,688
    const size_t WSZ = (size_t)EMBED * EMBED;     // 1,048,576

    bf16* p = (bf16*)d_ws;
    bf16* ch   = p; p += SZ;
    bf16* ccos = p; p += CS;
    bf16* csin = p; p += CS;
    bf16* cqw  = p; p += WSZ;
    bf16* ckw  = p; p += WSZ;
    bf16* cvw  = p; p += WSZ;
    bf16* cow  = p; p += WSZ;
    bf16* cqb  = p; p += EMBED;
    bf16* cvb  = p; p += EMBED;
    bf16* cob  = p; p += EMBED;
    bf16* wq   = p; p += SZ;      // Q (post-RoPE, pre-scaled), then attn out
    bf16* wk   = p; p += SZ;
    bf16* wvt  = p; p += SZ;      // V^T per head

    CvtArgs ca;
    const void* srcs[10] = {d_in[0], d_in[1], d_in[2], d_in[3], d_in[5],
                            d_in[6], d_in[8], d_in[4], d_in[7], d_in[9]};
    bf16* dsts[10] = {ch, ccos, csin, cqw, ckw, cvw, cow, cqb, cvb, cob};
    int   ns[10]   = {(int)SZ, (int)CS, (int)CS, (int)WSZ, (int)WSZ,
                      (int)WSZ, (int)WSZ, EMBED, EMBED, EMBED};
    int cum = 0;
    for (int i = 0; i < 10; ++i) {
        ca.src[i] = srcs[i]; ca.dst[i] = dsts[i]; ca.n[i] = ns[i];
        ca.cum[i] = cum;
        cum += (ns[i] + 2047) / 2048;
    }
    to_bf16_fused<<<cum, 256, 0, stream>>>(ca, disc);

    gemm_qkv<<<77 * 24, 256, 0, stream>>>(ch, cqw, ckw, cvw, cqb, cvb,
                                          ccos, csin, wq, wk, wvt, T_TOTAL);
    attn_kernel<<<1232, 512, 0, stream>>>(wq, wk, wvt, wq);
    gemm_out<<<77 * 8, 256, 0, stream>>>(wq, cow, cob, d_out, T_TOTAL, disc);
}